// Round 4
// baseline (585.460 us; speedup 1.0000x reference)
//
#include <hip/hip_runtime.h>
#include <stdint.h>

#define E_TOT 500000
#define EB 128
#define NBLK ((E_TOT + EB - 1) / EB)   // 3907
#define SWZ(e) (((e) & 7) << 4)

using u32x4 = __attribute__((ext_vector_type(4))) unsigned int;
using f32x4 = __attribute__((ext_vector_type(4))) float;

__device__ __forceinline__ uint32_t f2bf(float x) {
    uint32_t u = __builtin_bit_cast(uint32_t, x);
    return (u + 0x7fffu + ((u >> 16) & 1u)) >> 16;   // RNE, inputs finite
}
__device__ __forceinline__ uint32_t pk2(float a, float b) {
    return f2bf(a) | (f2bf(b) << 16);
}

// D = A*B + 0  (init form: src2 = inline constant 0)
__device__ __forceinline__ void mfma_f(f32x4& d, u32x4 a, u32x4 b) {
    asm("v_mfma_f32_16x16x32_bf16 %0, %1, %2, 0" : "=&v"(d) : "v"(a), "v"(b));
}
// D += A*B  (accumulate, src2 tied to dst)
__device__ __forceinline__ void mfma_a(f32x4& d, u32x4 a, u32x4 b) {
    asm("v_mfma_f32_16x16x32_bf16 %0, %1, %2, %0" : "+&v"(d) : "v"(a), "v"(b));
}

__global__ void prep_weights(const float* __restrict__ W1, const float* __restrict__ W2,
                             unsigned short* __restrict__ w1b, unsigned short* __restrict__ w2b) {
    int t = blockIdx.x * 256 + threadIdx.x;   // 65536 threads, 4 elems each
    int i = t * 4;
    if (i < 131072) {
        float4 f = *reinterpret_cast<const float4*>(W1 + i);
        uint2 u;
        u.x = pk2(f.x, f.y); u.y = pk2(f.z, f.w);
        *reinterpret_cast<uint2*>(w1b + i) = u;
    } else {
        int j = i - 131072;
        float4 f = *reinterpret_cast<const float4*>(W2 + j);
        uint2 u;
        u.x = pk2(f.x, f.y); u.y = pk2(f.z, f.w);
        *reinterpret_cast<uint2*>(w2b + j) = u;
    }
}

// Fused: gather+concat -> L1(256->512) -> L2(512->256) -> logits + intermediate store.
// h-transposed orientation: D = W * X^T so weights are A-operand (read once per block).
// PREPPED: w1p/w2p are bf16 [512][256]/[256][512]. Else: f32 W1/W2, converted in-register.
template<bool PREPPED>
__global__ __launch_bounds__(512, 2) void fused_mlp(
    const float* __restrict__ nf,
    const int* __restrict__ eidx,      // int32 per harness contract
    const char* __restrict__ w1p,
    const char* __restrict__ w2p,
    const float* __restrict__ b1,
    const float* __restrict__ b2,
    const float* __restrict__ w3,
    const float* __restrict__ b3,
    float* __restrict__ out)
{
    // region A = smem[0:64K]: X[128][256]bf16, later h1 k-local 0..255
    // region B = smem[64K:128K]: h1 k-local 256..511
    __shared__ __align__(16) char smem[131072];
    __shared__ float logit_lds[EB];

    const int tid  = threadIdx.x;
    const int lane = tid & 63;
    const int wid  = tid >> 6;       // 0..7
    const int hi   = lane >> 4;      // 0..3
    const int lo   = lane & 15;      // 0..15
    const long long e0 = (long long)blockIdx.x * EB;

    if (tid < EB) logit_lds[tid] = 0.f;

    // ---- gather + f32->bf16 + swizzled LDS stage: X[e][0:128]=nf[row], [128:256]=nf[col]
    {
        int e    = tid >> 2;          // 0..127
        int side = (tid >> 1) & 1;    // 0=row,1=col
        int half = tid & 1;           // which 64-feature half
        long long eg = e0 + e;
        int idx = 0;
        if (eg < E_TOT) idx = eidx[(size_t)side * E_TOT + (size_t)eg];
        const float4* src = reinterpret_cast<const float4*>(nf + (size_t)idx * 128 + half * 64);
        char* dstrow = smem + e * 512;
        const int ob = side * 256 + half * 128;
#pragma unroll
        for (int c = 0; c < 8; ++c) {
            float4 f0 = src[2 * c];
            float4 f1 = src[2 * c + 1];
            u32x4 u;
            u[0] = pk2(f0.x, f0.y); u[1] = pk2(f0.z, f0.w);
            u[2] = pk2(f1.x, f1.y); u[3] = pk2(f1.z, f1.w);
            *reinterpret_cast<u32x4*>(dstrow + ((ob + c * 16) ^ SWZ(e))) = u;
        }
    }
    __syncthreads();

    // ---- Layer 1: h1T[512][128] = W1 * X^T.  wave owns rows [wid*64, wid*64+64) (4 M-tiles)
    f32x4 acc1[4][8];
    {
#pragma unroll
        for (int kk = 0; kk < 8; ++kk) {
            u32x4 a[4], b[8];
            if constexpr (PREPPED) {
                const char* wb = w1p + (size_t)(wid * 64 + lo) * 512 + hi * 16;
#pragma unroll
                for (int mt = 0; mt < 4; ++mt)
                    a[mt] = *reinterpret_cast<const u32x4*>(wb + mt * 16 * 512 + kk * 64);
            } else {
                const float* W1f = reinterpret_cast<const float*>(w1p);
#pragma unroll
                for (int mt = 0; mt < 4; ++mt) {
                    const float* p = W1f + (size_t)(wid * 64 + mt * 16 + lo) * 256 + kk * 32 + hi * 8;
                    float4 f0 = *reinterpret_cast<const float4*>(p);
                    float4 f1 = *reinterpret_cast<const float4*>(p + 4);
                    a[mt][0] = pk2(f0.x, f0.y); a[mt][1] = pk2(f0.z, f0.w);
                    a[mt][2] = pk2(f1.x, f1.y); a[mt][3] = pk2(f1.z, f1.w);
                }
            }
#pragma unroll
            for (int nt = 0; nt < 8; ++nt) {
                int e = nt * 16 + lo;
                b[nt] = *reinterpret_cast<const u32x4*>(smem + e * 512 + ((kk * 64 + hi * 16) ^ SWZ(e)));
            }
            if constexpr (!PREPPED) {
                // VALU-write -> MFMA-read hazard fence (inline asm hides MFMA from
                // the hazard recognizer)
                __builtin_amdgcn_sched_barrier(0);
                asm volatile("s_nop 7");
                __builtin_amdgcn_sched_barrier(0);
            }
#pragma unroll
            for (int nt = 0; nt < 8; ++nt)
#pragma unroll
                for (int mt = 0; mt < 4; ++mt) {
                    if (kk == 0) mfma_f(acc1[mt][nt], a[mt], b[nt]);
                    else         mfma_a(acc1[mt][nt], a[mt], b[nt]);
                }
        }
    }
    // hazard fence: MFMA dest -> VALU reads
    __builtin_amdgcn_sched_barrier(0);
    asm volatile("s_nop 7\ns_nop 7");
    __builtin_amdgcn_sched_barrier(0);
    __syncthreads();   // everyone done reading X before overwriting region A

    // ---- bias+relu -> bf16 -> LDS h1 (swizzled).  m = wid*64 + mt*16 + hi*4 + r
    {
        char* dst = smem + ((wid >= 4) ? 65536 : 0);
        const int cb = (wid & 3) * 128;   // byte col base within region
#pragma unroll
        for (int mt = 0; mt < 4; ++mt) {
            const float4 bias = *reinterpret_cast<const float4*>(b1 + wid * 64 + mt * 16 + hi * 4);
            const int ob = cb + mt * 32 + hi * 8;
#pragma unroll
            for (int nt = 0; nt < 8; ++nt) {
                int e = nt * 16 + lo;
                f32x4 v = acc1[mt][nt];
                float r0 = fmaxf(v[0] + bias.x, 0.f);
                float r1 = fmaxf(v[1] + bias.y, 0.f);
                float r2 = fmaxf(v[2] + bias.z, 0.f);
                float r3 = fmaxf(v[3] + bias.w, 0.f);
                uint2 u;
                u.x = pk2(r0, r1); u.y = pk2(r2, r3);
                *reinterpret_cast<uint2*>(dst + e * 512 + (ob ^ SWZ(e))) = u;
            }
        }
    }
    __syncthreads();

    // ---- Layer 2: h2T[256][128] = W2 * h1T.  wave: rows (wid&3)*64.. (4 M-tiles),
    //      edges (wid>>2)*64.. (4 N-tiles).  K = 512 over two LDS regions.
    f32x4 acc2[4][4];
    {
        const int eg0 = (wid >> 2) * 64;
#pragma unroll
        for (int kh = 0; kh < 2; ++kh) {
            const char* hb = smem + kh * 65536;
#pragma unroll
            for (int kk = 0; kk < 8; ++kk) {
                u32x4 a[4], b[4];
                if constexpr (PREPPED) {
                    const char* wb = w2p + (size_t)((wid & 3) * 64 + lo) * 1024 + hi * 16;
#pragma unroll
                    for (int mt = 0; mt < 4; ++mt)
                        a[mt] = *reinterpret_cast<const u32x4*>(wb + mt * 16 * 1024 + kh * 512 + kk * 64);
                } else {
                    const float* W2f = reinterpret_cast<const float*>(w2p);
#pragma unroll
                    for (int mt = 0; mt < 4; ++mt) {
                        const float* p = W2f + (size_t)((wid & 3) * 64 + mt * 16 + lo) * 512 + kh * 256 + kk * 32 + hi * 8;
                        float4 f0 = *reinterpret_cast<const float4*>(p);
                        float4 f1 = *reinterpret_cast<const float4*>(p + 4);
                        a[mt][0] = pk2(f0.x, f0.y); a[mt][1] = pk2(f0.z, f0.w);
                        a[mt][2] = pk2(f1.x, f1.y); a[mt][3] = pk2(f1.z, f1.w);
                    }
                }
#pragma unroll
                for (int nt = 0; nt < 4; ++nt) {
                    int e = eg0 + nt * 16 + lo;
                    b[nt] = *reinterpret_cast<const u32x4*>(hb + e * 512 + ((kk * 64 + hi * 16) ^ SWZ(e)));
                }
                if constexpr (!PREPPED) {
                    __builtin_amdgcn_sched_barrier(0);
                    asm volatile("s_nop 7");
                    __builtin_amdgcn_sched_barrier(0);
                }
#pragma unroll
                for (int nt = 0; nt < 4; ++nt)
#pragma unroll
                    for (int mt = 0; mt < 4; ++mt) {
                        if (kh == 0 && kk == 0) mfma_f(acc2[mt][nt], a[mt], b[nt]);
                        else                    mfma_a(acc2[mt][nt], a[mt], b[nt]);
                    }
            }
        }
    }
    __builtin_amdgcn_sched_barrier(0);
    asm volatile("s_nop 7\ns_nop 7");
    __builtin_amdgcn_sched_barrier(0);

    // ---- epilogue: bias+relu, store intermediate (f32), logits via w3 dot
    {
        float* inter = out + E_TOT;
        const int eg0 = (wid >> 2) * 64;
        const int m0  = (wid & 3) * 64;
        float pls[4] = {0.f, 0.f, 0.f, 0.f};
#pragma unroll
        for (int mt = 0; mt < 4; ++mt) {
            const int m = m0 + mt * 16 + hi * 4;
            const float4 bias = *reinterpret_cast<const float4*>(b2 + m);
            const float4 wv   = *reinterpret_cast<const float4*>(w3 + m);
#pragma unroll
            for (int nt = 0; nt < 4; ++nt) {
                long long eg = e0 + eg0 + nt * 16 + lo;
                f32x4 v = acc2[mt][nt];
                float4 h;
                h.x = fmaxf(v[0] + bias.x, 0.f);
                h.y = fmaxf(v[1] + bias.y, 0.f);
                h.z = fmaxf(v[2] + bias.z, 0.f);
                h.w = fmaxf(v[3] + bias.w, 0.f);
                if (eg < E_TOT)
                    *reinterpret_cast<float4*>(inter + (size_t)eg * 256 + m) = h;
                pls[nt] += h.x * wv.x + h.y * wv.y + h.z * wv.z + h.w * wv.w;
            }
        }
#pragma unroll
        for (int nt = 0; nt < 4; ++nt) {
            float p = pls[nt];
            p += __shfl_xor(p, 16);
            p += __shfl_xor(p, 32);
            if (hi == 0) atomicAdd(&logit_lds[eg0 + nt * 16 + lo], p);
        }
    }
    __syncthreads();
    if (tid < EB) {
        long long eg = e0 + tid;
        if (eg < E_TOT) out[eg] = logit_lds[tid] + b3[0];
    }
}

extern "C" void kernel_launch(void* const* d_in, const int* in_sizes, int n_in,
                              void* d_out, int out_size, void* d_ws, size_t ws_size,
                              hipStream_t stream) {
    const float* nf   = (const float*)d_in[0];
    const int*   eidx = (const int*)d_in[1];     // int64 in reference -> int32 in harness
    const float* W1   = (const float*)d_in[2];
    const float* b1   = (const float*)d_in[3];
    const float* W2   = (const float*)d_in[4];
    const float* b2   = (const float*)d_in[5];
    const float* W3   = (const float*)d_in[6];
    const float* b3   = (const float*)d_in[7];
    float* out = (float*)d_out;

    const size_t need = (size_t)(512 * 256 + 256 * 512) * 2;   // 512 KB bf16 weights
    if (ws_size >= need) {
        unsigned short* w1b = (unsigned short*)d_ws;
        unsigned short* w2b = w1b + 512 * 256;
        prep_weights<<<256, 256, 0, stream>>>(W1, W2, w1b, w2b);
        fused_mlp<true><<<NBLK, 512, 0, stream>>>(nf, eidx, (const char*)w1b, (const char*)w2b,
                                                  b1, b2, W3, b3, out);
    } else {
        fused_mlp<false><<<NBLK, 512, 0, stream>>>(nf, eidx, (const char*)W1, (const char*)W2,
                                                   b1, b2, W3, b3, out);
    }
}